// Round 3
// baseline (414.098 us; speedup 1.0000x reference)
//
#include <hip/hip_runtime.h>

#define H    128
#define WP   130
#define NCH  256
#define NB   24
#define NIMG 6144          // NB * NCH
#define QPI  4225          // 16900 / 4 float4 per image
#define BPF  516           // border pixels per face image
#define TBLN 3096          // 6 * 516

// Face order: back(0), down(1), front(2), left(3), right(4), top(5)
__constant__ int c_R[6][9] = {
  {-1,0,0,  0,1,0,  0,0,-1},   // back  = Ry(pi)
  { 1,0,0,  0,0,-1, 0,1,0 },   // down  = Rx(pi/2)
  { 1,0,0,  0,1,0,  0,0,1 },   // front = I
  { 0,0,1,  0,1,0, -1,0,0 },   // left  = Ry(pi/2)
  { 0,0,-1, 0,1,0,  1,0,0 },   // right = Ry(-pi/2)
  { 1,0,0,  0,0,1,  0,-1,0},   // top   = Rx(-pi/2)
};
// NEIGHBORS[face][side], side order: up(0), down(1), left(2), right(3)
__constant__ int c_conn[6][4] = {
  {5,1,4,3}, {2,0,3,4}, {5,1,3,4}, {5,1,0,2}, {5,1,2,0}, {0,2,3,4},
};

#define INV_FP (65.0f / 4128.0f)

// ---------------- kernel A: build border table (3096 entries) ------------
// Per (face, border-k): source face (-1 if masked), 4 gather indices, 4 weights.
__global__ void __launch_bounds__(256)
border_table_kernel(int* __restrict__ tb_face, int4* __restrict__ tb_idx,
                    float4* __restrict__ tb_w) {
  int t = blockIdx.x * 256 + threadIdx.x;
  if (t >= TBLN) return;
  int face = t / BPF;
  int k    = t - face * BPF;

  int r, c;
  if (k < 130)      { r = 0;        c = k; }
  else if (k < 260) { r = WP - 1;   c = k - 130; }
  else if (k < 388) { r = k - 259;  c = 0; }
  else              { r = k - 387;  c = WP - 1; }

  int fs = -1;
  int4  idx = make_int4(0, 0, 0, 0);
  float4 w  = make_float4(0.f, 0.f, 0.f, 0.f);

  // candidate sides, priority: right(3) > left(2) > down(1) > up(0)
  int cand[2]; int nc = 0;
  if (c == WP - 1) cand[nc++] = 3;
  if (c == 0)      cand[nc++] = 2;
  if (r == WP - 1) cand[nc++] = 1;
  if (r == 0)      cand[nc++] = 0;

  float uc = ((float)c - 64.5f) * INV_FP;
  float ur = ((float)r - 64.5f) * INV_FP;

  for (int kk = 0; kk < nc; ++kk) {
    int s  = cand[kk];
    int cf = c_conn[face][s];
    const int* Rc = c_R[cf];
    const int* Rf = c_R[face];
    float g[3];
    #pragma unroll
    for (int i = 0; i < 3; ++i) {
      float acc = 0.0f;
      #pragma unroll
      for (int j = 0; j < 3; ++j) {
        int rr = Rc[i*3+0]*Rf[j*3+0] + Rc[i*3+1]*Rf[j*3+1] + Rc[i*3+2]*Rf[j*3+2];
        float dj = (j == 0) ? uc : (j == 1) ? ur : 1.0f;
        acc += (float)rr * dj;
      }
      g[i] = acc;
    }
    float x = g[0] / g[2];
    float y = g[1] / g[2];
    if (fabsf(x) <= 1.01f && fabsf(y) <= 1.01f) {
      x = fminf(fmaxf(x, -1.0f), 1.0f);
      y = fminf(fmaxf(y, -1.0f), 1.0f);
      float xp = (x + 1.0f) * 0.5f * (float)(H - 1);
      float yp = (y + 1.0f) * 0.5f * (float)(H - 1);
      float x0 = floorf(xp), y0 = floorf(yp);
      float wx = xp - x0,    wy = yp - y0;
      int x0i = min(max((int)x0, 0), H - 1);
      int x1i = min(x0i + 1, H - 1);
      int y0i = min(max((int)y0, 0), H - 1);
      int y1i = min(y0i + 1, H - 1);
      fs  = cf;
      idx = make_int4(y0i * H + x0i, y0i * H + x1i, y1i * H + x0i, y1i * H + x1i);
      w   = make_float4((1.f - wx) * (1.f - wy), wx * (1.f - wy),
                        (1.f - wx) * wy,         wx * wy);
      break;
    }
  }
  tb_face[t] = fs;
  tb_idx[t]  = idx;
  tb_w[t]    = w;
}

// ---------------- kernel B: output-centric, aligned float4 stores --------
// grid (17, 6144): blockIdx.y = image (n*256+ch), 17*256 threads cover 4225
// float4 quads. Interior elements: scalar load from input. Border: table.
__global__ void __launch_bounds__(256)
spherepad_out_kernel(const float* __restrict__ in, float4* __restrict__ out4,
                     const int* __restrict__ tb_face,
                     const int4* __restrict__ tb_idx,
                     const float4* __restrict__ tb_w) {
  unsigned q   = blockIdx.x * 256u + threadIdx.x;
  unsigned img = blockIdx.y;
  if (q >= QPI) return;

  unsigned p       = q << 2;            // element offset within image
  unsigned base_in = img << 14;         // img * 16384
  unsigned n       = img >> 8;          // 0..23
  unsigned ch      = img & 255u;
  unsigned rep     = n / 6u;
  unsigned face    = n - rep * 6u;

  float vals[4];
  #pragma unroll
  for (int j = 0; j < 4; ++j) {
    unsigned pj = p + (unsigned)j;
    unsigned r  = pj / 130u;            // compiler magic-mul
    unsigned c  = pj - r * 130u;
    if ((r - 1u) < 128u && (c - 1u) < 128u) {
      vals[j] = in[base_in + ((r - 1u) << 7) + (c - 1u)];
    } else {
      unsigned tk = (r == 0u)   ? c
                  : (r == 129u) ? (130u + c)
                  : (c == 0u)   ? (259u + r)
                  :               (387u + r);
      unsigned ti = face * (unsigned)BPF + tk;
      int fs = tb_face[ti];
      float v = 0.0f;
      if (fs >= 0) {
        int4   id = tb_idx[ti];
        float4 w  = tb_w[ti];
        unsigned src = (((rep * 6u + (unsigned)fs) << 8) + ch) << 14;
        v = w.x * in[src + (unsigned)id.x]
          + w.y * in[src + (unsigned)id.y]
          + w.z * in[src + (unsigned)id.z]
          + w.w * in[src + (unsigned)id.w];
      }
      vals[j] = v;
    }
  }
  out4[img * (unsigned)QPI + q] = make_float4(vals[0], vals[1], vals[2], vals[3]);
}

// ---------------- fallback (round-2 kernels) if d_ws is too small --------
__global__ void __launch_bounds__(256)
interior_kernel(const float4* __restrict__ in4, float* __restrict__ out) {
  unsigned t = blockIdx.x * 256u + threadIdx.x;
  unsigned c4  = t & 31u;
  unsigned r   = (t >> 5) & 127u;
  unsigned img = t >> 12;
  float4 v = in4[t];
  unsigned o = img * 16900u + (r + 1u) * 130u + 1u + (c4 << 2);
  out[o] = v.x; out[o + 1] = v.y; out[o + 2] = v.z; out[o + 3] = v.w;
}

__global__ void __launch_bounds__(256)
border_kernel(const float* __restrict__ in, float* __restrict__ out) {
  unsigned tid = blockIdx.x * 256u + threadIdx.x;
  const unsigned total = 6144u * 516u;
  if (tid >= total) return;
  unsigned img = tid / 516u;
  unsigned k   = tid - img * 516u;
  int r, c;
  if (k < 130u)      { r = 0;               c = (int)k; }
  else if (k < 260u) { r = WP - 1;          c = (int)(k - 130u); }
  else if (k < 388u) { r = (int)(k - 259u); c = 0; }
  else               { r = (int)(k - 387u); c = WP - 1; }
  int n = (int)(img >> 8), ch = (int)(img & 255u);
  int face = n % 6, rep = n / 6;
  float v = 0.0f;
  int cand[2]; int nc = 0;
  if (c == WP - 1) cand[nc++] = 3;
  if (c == 0)      cand[nc++] = 2;
  if (r == WP - 1) cand[nc++] = 1;
  if (r == 0)      cand[nc++] = 0;
  float uc = ((float)c - 64.5f) * INV_FP;
  float ur = ((float)r - 64.5f) * INV_FP;
  for (int kk = 0; kk < nc; ++kk) {
    int s = cand[kk], cf = c_conn[face][s];
    const int* Rc = c_R[cf]; const int* Rf = c_R[face];
    float g[3];
    #pragma unroll
    for (int i = 0; i < 3; ++i) {
      float acc = 0.0f;
      #pragma unroll
      for (int j = 0; j < 3; ++j) {
        int rr = Rc[i*3+0]*Rf[j*3+0] + Rc[i*3+1]*Rf[j*3+1] + Rc[i*3+2]*Rf[j*3+2];
        float dj = (j == 0) ? uc : (j == 1) ? ur : 1.0f;
        acc += (float)rr * dj;
      }
      g[i] = acc;
    }
    float x = g[0] / g[2], y = g[1] / g[2];
    if (fabsf(x) <= 1.01f && fabsf(y) <= 1.01f) {
      x = fminf(fmaxf(x, -1.0f), 1.0f);
      y = fminf(fmaxf(y, -1.0f), 1.0f);
      const float* src = in + ((size_t)((rep * 6 + cf) * NCH + ch)) * H * H;
      float xp = (x + 1.0f) * 0.5f * (float)(H - 1);
      float yp = (y + 1.0f) * 0.5f * (float)(H - 1);
      float x0 = floorf(xp), y0 = floorf(yp);
      float wx = xp - x0, wy = yp - y0;
      int x0i = min(max((int)x0, 0), H - 1);
      int x1i = min(x0i + 1, H - 1);
      int y0i = min(max((int)y0, 0), H - 1);
      int y1i = min(y0i + 1, H - 1);
      v = src[y0i*H+x0i]*(1.f-wx)*(1.f-wy) + src[y0i*H+x1i]*wx*(1.f-wy)
        + src[y1i*H+x0i]*(1.f-wx)*wy       + src[y1i*H+x1i]*wx*wy;
      break;
    }
  }
  out[(unsigned)img * 16900u + (unsigned)r * 130u + (unsigned)c] = v;
}

extern "C" void kernel_launch(void* const* d_in, const int* in_sizes, int n_in,
                              void* d_out, int out_size, void* d_ws, size_t ws_size,
                              hipStream_t stream) {
  (void)in_sizes; (void)n_in; (void)out_size;
  const float* in = (const float*)d_in[0];
  float* out = (float*)d_out;

  const size_t need = (size_t)TBLN * (4 + 16 + 16);   // 111,456 B
  if (d_ws != nullptr && ws_size >= need) {
    int*    tb_face = (int*)d_ws;
    int4*   tb_idx  = (int4*)(tb_face + TBLN);
    float4* tb_w    = (float4*)(tb_idx + TBLN);
    border_table_kernel<<<(TBLN + 255) / 256, 256, 0, stream>>>(tb_face, tb_idx, tb_w);
    dim3 grid((QPI + 255) / 256, NIMG);
    spherepad_out_kernel<<<grid, 256, 0, stream>>>(in, (float4*)out,
                                                   tb_face, tb_idx, tb_w);
  } else {
    interior_kernel<<<98304, 256, 0, stream>>>((const float4*)in, out);
    const unsigned btotal = 6144u * 516u;
    border_kernel<<<(btotal + 255u) / 256u, 256, 0, stream>>>(in, out);
  }
}

// Round 4
// 329.713 us; speedup vs baseline: 1.2559x; 1.2559x over previous
//
#include <hip/hip_runtime.h>

#define H    128
#define WP   130
#define NCH  256
#define NIMG 6144          // 24 * 256
#define QPI  4225          // 16900/4 float4 per output image
#define BPF  516           // border pixels per face image
#define TBLN 3096          // 6 * 516

// Face order: back(0), down(1), front(2), left(3), right(4), top(5)
__constant__ int c_R[6][9] = {
  {-1,0,0,  0,1,0,  0,0,-1},
  { 1,0,0,  0,0,-1, 0,1,0 },
  { 1,0,0,  0,1,0,  0,0,1 },
  { 0,0,1,  0,1,0, -1,0,0 },
  { 0,0,-1, 0,1,0,  1,0,0 },
  { 1,0,0,  0,0,1,  0,-1,0},
};
// NEIGHBORS[face][side], side order: up(0), down(1), left(2), right(3)
__constant__ int c_conn[6][4] = {
  {5,1,4,3}, {2,0,3,4}, {5,1,3,4}, {5,1,0,2}, {5,1,2,0}, {0,2,3,4},
};

#define INV_FP (65.0f / 4128.0f)

// ---------- kernel A: build border table (3096 entries, runs in ~2us) ----
__global__ void __launch_bounds__(256)
border_table_kernel(int* __restrict__ tb_face, int4* __restrict__ tb_idx,
                    float4* __restrict__ tb_w) {
  int t = blockIdx.x * 256 + threadIdx.x;
  if (t >= TBLN) return;
  int face = t / BPF;
  int k    = t - face * BPF;

  int r, c;
  if (k < 130)      { r = 0;        c = k; }
  else if (k < 260) { r = WP - 1;   c = k - 130; }
  else if (k < 388) { r = k - 259;  c = 0; }
  else              { r = k - 387;  c = WP - 1; }

  int fs = -1;
  int4  idx = make_int4(0, 0, 0, 0);
  float4 w  = make_float4(0.f, 0.f, 0.f, 0.f);

  int cand[2]; int nc = 0;
  if (c == WP - 1) cand[nc++] = 3;
  if (c == 0)      cand[nc++] = 2;
  if (r == WP - 1) cand[nc++] = 1;
  if (r == 0)      cand[nc++] = 0;

  float uc = ((float)c - 64.5f) * INV_FP;
  float ur = ((float)r - 64.5f) * INV_FP;

  for (int kk = 0; kk < nc; ++kk) {
    int s  = cand[kk];
    int cf = c_conn[face][s];
    const int* Rc = c_R[cf];
    const int* Rf = c_R[face];
    float g[3];
    #pragma unroll
    for (int i = 0; i < 3; ++i) {
      float acc = 0.0f;
      #pragma unroll
      for (int j = 0; j < 3; ++j) {
        int rr = Rc[i*3+0]*Rf[j*3+0] + Rc[i*3+1]*Rf[j*3+1] + Rc[i*3+2]*Rf[j*3+2];
        float dj = (j == 0) ? uc : (j == 1) ? ur : 1.0f;
        acc += (float)rr * dj;
      }
      g[i] = acc;
    }
    float x = g[0] / g[2];
    float y = g[1] / g[2];
    if (fabsf(x) <= 1.01f && fabsf(y) <= 1.01f) {
      x = fminf(fmaxf(x, -1.0f), 1.0f);
      y = fminf(fmaxf(y, -1.0f), 1.0f);
      float xp = (x + 1.0f) * 0.5f * (float)(H - 1);
      float yp = (y + 1.0f) * 0.5f * (float)(H - 1);
      float x0 = floorf(xp), y0 = floorf(yp);
      float wx = xp - x0,    wy = yp - y0;
      int x0i = min(max((int)x0, 0), H - 1);
      int x1i = min(x0i + 1, H - 1);
      int y0i = min(max((int)y0, 0), H - 1);
      int y1i = min(y0i + 1, H - 1);
      fs  = cf;
      idx = make_int4(y0i * H + x0i, y0i * H + x1i, y1i * H + x0i, y1i * H + x1i);
      w   = make_float4((1.f - wx) * (1.f - wy), wx * (1.f - wy),
                        (1.f - wx) * wy,         wx * wy);
      break;
    }
  }
  tb_face[t] = fs;
  tb_idx[t]  = idx;
  tb_w[t]    = w;
}

// ---------- kernel B: fast interior — aligned loads AND aligned stores ---
// One thread per output-aligned quad fully inside an interior row.
// r even: 31 quads (cols 4..127), shift s=3; r odd: 30 quads (cols 6..125), s=1.
// Input idx i0 = 4*qq - 2r - 129; load aligned A=in4[i0>>2], B=next, select.
__global__ void __launch_bounds__(256)
fast_interior_kernel(const float4* __restrict__ in4, float4* __restrict__ out4) {
  unsigned t = blockIdx.x * 256u + threadIdx.x;   // exactly 6144*128*31
  unsigned qi  = t % 31u;
  unsigned tmp = t / 31u;
  unsigned r   = (tmp & 127u) + 1u;               // 1..128
  unsigned img = tmp >> 7;

  unsigned m   = r >> 1;
  unsigned odd = r & 1u;
  if (odd && qi == 30u) return;                   // odd rows have 30 quads
  unsigned qq = 65u * m + (odd ? 34u : 1u) + qi;
  unsigned i0 = (qq << 2) - 2u * r - 129u;
  unsigned ib = i0 >> 2;

  const float4* base = in4 + ((size_t)img << 12); // img * 4096 quads
  float4 A = base[ib];
  float4 B = base[ib + 1u];
  float4 o;
  if (odd) {        // s = 1
    o = make_float4(A.y, A.z, A.w, B.x);
  } else {          // s = 3
    o = make_float4(A.w, B.x, B.y, B.z);
  }
  out4[(size_t)img * QPI + qq] = o;
}

// ---------- kernel C: fringe — interior cols not covered by kernel B -----
// r even: cols {1,2,3,128}; r odd: cols {1..5,126,127,128}. Pure copies.
__global__ void __launch_bounds__(256)
fringe_kernel(const float* __restrict__ in, float* __restrict__ out) {
  unsigned t = blockIdx.x * 256u + threadIdx.x;   // exactly 6144*128*8
  unsigned slot = t & 7u;
  unsigned r    = ((t >> 3) & 127u) + 1u;         // 1..128
  unsigned img  = t >> 10;

  unsigned c;
  if (r & 1u) {
    c = (slot < 5u) ? (1u + slot) : (121u + slot);   // 1..5, 126,127,128
  } else {
    if (slot >= 4u) return;
    c = (slot < 3u) ? (1u + slot) : 128u;            // 1,2,3,128
  }
  out[img * 16900u + r * 130u + c] =
      in[(img << 14) + ((r - 1u) << 7) + (c - 1u)];
}

// ---------- kernel D: border ring via table ------------------------------
__global__ void __launch_bounds__(256)
border_tab_kernel(const float* __restrict__ in, float* __restrict__ out,
                  const int* __restrict__ tb_face,
                  const int4* __restrict__ tb_idx,
                  const float4* __restrict__ tb_w) {
  unsigned tid = blockIdx.x * 256u + threadIdx.x;  // exactly 6144*516
  unsigned img = tid / (unsigned)BPF;
  unsigned k   = tid - img * (unsigned)BPF;

  unsigned n    = img >> 8;
  unsigned ch   = img & 255u;
  unsigned rep  = n / 6u;
  unsigned face = n - rep * 6u;

  unsigned ti = face * (unsigned)BPF + k;
  int fs = tb_face[ti];
  float v = 0.0f;
  if (fs >= 0) {
    int4   id = tb_idx[ti];
    float4 w  = tb_w[ti];
    unsigned src = (((rep * 6u + (unsigned)fs) << 8) + ch) << 14;
    v = w.x * in[src + (unsigned)id.x]
      + w.y * in[src + (unsigned)id.y]
      + w.z * in[src + (unsigned)id.z]
      + w.w * in[src + (unsigned)id.w];
  }
  unsigned p;
  if (k < 130u)      p = k;
  else if (k < 260u) p = 129u * 130u + (k - 130u);
  else if (k < 388u) p = (k - 259u) * 130u;
  else               p = (k - 387u) * 130u + 129u;
  out[img * 16900u + p] = v;
}

// ---------- fallback (round-2 kernels) if d_ws unavailable ---------------
__global__ void __launch_bounds__(256)
interior_kernel(const float4* __restrict__ in4, float* __restrict__ out) {
  unsigned t = blockIdx.x * 256u + threadIdx.x;
  unsigned c4  = t & 31u;
  unsigned r   = (t >> 5) & 127u;
  unsigned img = t >> 12;
  float4 v = in4[t];
  unsigned o = img * 16900u + (r + 1u) * 130u + 1u + (c4 << 2);
  out[o] = v.x; out[o + 1] = v.y; out[o + 2] = v.z; out[o + 3] = v.w;
}

__global__ void __launch_bounds__(256)
border_kernel(const float* __restrict__ in, float* __restrict__ out) {
  unsigned tid = blockIdx.x * 256u + threadIdx.x;
  const unsigned total = 6144u * 516u;
  if (tid >= total) return;
  unsigned img = tid / 516u;
  unsigned k   = tid - img * 516u;
  int r, c;
  if (k < 130u)      { r = 0;               c = (int)k; }
  else if (k < 260u) { r = WP - 1;          c = (int)(k - 130u); }
  else if (k < 388u) { r = (int)(k - 259u); c = 0; }
  else               { r = (int)(k - 387u); c = WP - 1; }
  int n = (int)(img >> 8), ch = (int)(img & 255u);
  int face = n % 6, rep = n / 6;
  float v = 0.0f;
  int cand[2]; int nc = 0;
  if (c == WP - 1) cand[nc++] = 3;
  if (c == 0)      cand[nc++] = 2;
  if (r == WP - 1) cand[nc++] = 1;
  if (r == 0)      cand[nc++] = 0;
  float uc = ((float)c - 64.5f) * INV_FP;
  float ur = ((float)r - 64.5f) * INV_FP;
  for (int kk = 0; kk < nc; ++kk) {
    int s = cand[kk], cf = c_conn[face][s];
    const int* Rc = c_R[cf]; const int* Rf = c_R[face];
    float g[3];
    #pragma unroll
    for (int i = 0; i < 3; ++i) {
      float acc = 0.0f;
      #pragma unroll
      for (int j = 0; j < 3; ++j) {
        int rr = Rc[i*3+0]*Rf[j*3+0] + Rc[i*3+1]*Rf[j*3+1] + Rc[i*3+2]*Rf[j*3+2];
        float dj = (j == 0) ? uc : (j == 1) ? ur : 1.0f;
        acc += (float)rr * dj;
      }
      g[i] = acc;
    }
    float x = g[0] / g[2], y = g[1] / g[2];
    if (fabsf(x) <= 1.01f && fabsf(y) <= 1.01f) {
      x = fminf(fmaxf(x, -1.0f), 1.0f);
      y = fminf(fmaxf(y, -1.0f), 1.0f);
      const float* src = in + ((size_t)((rep * 6 + cf) * NCH + ch)) * H * H;
      float xp = (x + 1.0f) * 0.5f * (float)(H - 1);
      float yp = (y + 1.0f) * 0.5f * (float)(H - 1);
      float x0 = floorf(xp), y0 = floorf(yp);
      float wx = xp - x0, wy = yp - y0;
      int x0i = min(max((int)x0, 0), H - 1);
      int x1i = min(x0i + 1, H - 1);
      int y0i = min(max((int)y0, 0), H - 1);
      int y1i = min(y0i + 1, H - 1);
      v = src[y0i*H+x0i]*(1.f-wx)*(1.f-wy) + src[y0i*H+x1i]*wx*(1.f-wy)
        + src[y1i*H+x0i]*(1.f-wx)*wy       + src[y1i*H+x1i]*wx*wy;
      break;
    }
  }
  out[(unsigned)img * 16900u + (unsigned)r * 130u + (unsigned)c] = v;
}

extern "C" void kernel_launch(void* const* d_in, const int* in_sizes, int n_in,
                              void* d_out, int out_size, void* d_ws, size_t ws_size,
                              hipStream_t stream) {
  (void)in_sizes; (void)n_in; (void)out_size;
  const float* in = (const float*)d_in[0];
  float* out = (float*)d_out;

  const size_t need = (size_t)TBLN * (4 + 16 + 16);   // 111,456 B
  if (d_ws != nullptr && ws_size >= need) {
    int*    tb_face = (int*)d_ws;
    int4*   tb_idx  = (int4*)(tb_face + TBLN);
    float4* tb_w    = (float4*)(tb_idx + TBLN);
    border_table_kernel<<<(TBLN + 255) / 256, 256, 0, stream>>>(tb_face, tb_idx, tb_w);

    // interior quads: 6144 * 128 * 31 = 24,379,392 threads = 95232 blocks
    fast_interior_kernel<<<95232, 256, 0, stream>>>((const float4*)in,
                                                    (float4*)out);
    // fringe: 6144 * 128 * 8 = 6,291,456 threads = 24576 blocks
    fringe_kernel<<<24576, 256, 0, stream>>>(in, out);
    // border: 6144 * 516 = 3,170,304 threads = 12384 blocks
    border_tab_kernel<<<12384, 256, 0, stream>>>(in, out, tb_face, tb_idx, tb_w);
  } else {
    interior_kernel<<<98304, 256, 0, stream>>>((const float4*)in, out);
    const unsigned btotal = 6144u * 516u;
    border_kernel<<<(btotal + 255u) / 256u, 256, 0, stream>>>(in, out);
  }
}